// Round 21
// baseline (2086.981 us; speedup 1.0000x reference)
//
#include <hip/hip_runtime.h>
#include <hip/hip_bf16.h>
#include <cfloat>
#include <cmath>

typedef __bf16 bf16x8 __attribute__((ext_vector_type(8)));
typedef __bf16 bf16x4 __attribute__((ext_vector_type(4)));
typedef float  f32x4  __attribute__((ext_vector_type(4)));

static constexpr int Bb = 2, Nn = 1024, Dd = 768, Hh = 12, HDd = 64, FFf = 3072, NLl = 12, NCc = 1000;
static constexpr int Mm = Bb * Nn; // 2048
static constexpr int NS = 4;       // flash KV splits
static constexpr float NEGF = -3.402823466e38f;

// ---------- reductions (256-thread blocks = 4 waves) ----------
__device__ __forceinline__ float block_reduce_sum(float v, volatile float* smem) {
  for (int o = 32; o; o >>= 1) v += __shfl_down(v, o);
  int lane = threadIdx.x & 63, w = threadIdx.x >> 6;
  __syncthreads();
  if (lane == 0) smem[w] = v;
  __syncthreads();
  return smem[0] + smem[1] + smem[2] + smem[3];
}

__device__ __forceinline__ float block_reduce_max(float v, volatile float* smem) {
  for (int o = 32; o; o >>= 1) v = fmaxf(v, __shfl_down(v, o));
  int lane = threadIdx.x & 63, w = threadIdx.x >> 6;
  __syncthreads();
  if (lane == 0) smem[w] = v;
  __syncthreads();
  return fmaxf(fmaxf(smem[0], smem[1]), fmaxf(smem[2], smem[3]));
}

// ---------- mask dtype detection: 0=int32 1=bytes 2=f32 3=int64 4=bf16 ----------
__global__ void detect_mask(const unsigned char* __restrict__ m, int* __restrict__ flag) {
  __shared__ int s_nz1, s_nz2, s_nz3, s_nz84, s_pv;
  int tid = threadIdx.x;
  if (tid == 0) { s_nz1 = 0; s_nz2 = 0; s_nz3 = 0; s_nz84 = 0; s_pv = 0; }
  __syncthreads();
  int nz1 = 0, nz2 = 0, nz3 = 0, nz84 = 0, pv = 0;
  for (int i = tid; i < 2048; i += 256) {
    unsigned char v = m[i];
    if (v) {
      int p4 = i & 3;
      if (p4 == 1) nz1 = 1;
      if (p4 == 2) nz2 = 1;
      if (p4 == 3) nz3 = 1;
      if ((i & 7) == 4) nz84 = 1;
      if ((i & 1) == 0) { if (v != 0x80) pv = 1; }
      else              { if (v != 0x3f) pv = 1; }
    }
  }
  if (nz1)  atomicOr(&s_nz1, 1);
  if (nz2)  atomicOr(&s_nz2, 1);
  if (nz3)  atomicOr(&s_nz3, 1);
  if (nz84) atomicOr(&s_nz84, 1);
  if (pv)   atomicOr(&s_pv, 1);
  __syncthreads();
  if (tid == 0) {
    int f;
    if (!s_nz1 && !s_nz2 && !s_nz3) f = s_nz84 ? 0 : 3;
    else if (!s_pv)                 f = s_nz1 ? 4 : 2;
    else                            f = 1;
    *flag = f;
  }
}

__device__ __forceinline__ bool mask_at(const void* mraw, int flag, int idx) {
  switch (flag) {
    case 0:  return ((const int*)mraw)[idx] != 0;
    case 1:  return ((const unsigned char*)mraw)[idx] != 0;
    case 2:  return ((const float*)mraw)[idx] != 0.f;
    case 3:  return ((const long long*)mraw)[idx] != 0;
    default: return ((const unsigned short*)mraw)[idx] != 0;
  }
}

// ---------- weight f32 -> bf16 (8 elems/thread) ----------
__device__ __forceinline__ void cvt8_store(const float* __restrict__ s, __bf16* __restrict__ d, int j) {
  float4 f0 = reinterpret_cast<const float4*>(s)[j * 2];
  float4 f1 = reinterpret_cast<const float4*>(s)[j * 2 + 1];
  bf16x8 r;
  r[0] = (__bf16)f0.x; r[1] = (__bf16)f0.y; r[2] = (__bf16)f0.z; r[3] = (__bf16)f0.w;
  r[4] = (__bf16)f1.x; r[5] = (__bf16)f1.y; r[6] = (__bf16)f1.z; r[7] = (__bf16)f1.w;
  reinterpret_cast<bf16x8*>(d)[j] = r;
}

__global__ __launch_bounds__(256) void cvt_w(const float* __restrict__ src, __bf16* __restrict__ dst, int n8) {
  int i = blockIdx.x * 256 + threadIdx.x;
  if (i < n8) cvt8_store(src, dst, i);
}

__global__ __launch_bounds__(256) void cvt_w4(const float* __restrict__ sq, const float* __restrict__ sp,
                                              const float* __restrict__ s1, const float* __restrict__ s2,
                                              __bf16* __restrict__ dq, __bf16* __restrict__ dp,
                                              __bf16* __restrict__ d1, __bf16* __restrict__ d2) {
  const int N0 = Dd * 3 * Dd / 8, N1 = Dd * Dd / 8, N2 = Dd * FFf / 8, N3 = FFf * Dd / 8;
  int i = blockIdx.x * 256 + threadIdx.x;
  if (i < N0)                    cvt8_store(sq, dq, i);
  else if (i < N0 + N1)          cvt8_store(sp, dp, i - N0);
  else if (i < N0 + N1 + N2)     cvt8_store(s1, d1, i - N0 - N1);
  else if (i < N0 + N1 + N2 + N3) cvt8_store(s2, d2, i - N0 - N1 - N2);
}

// ---------- h = x + pe (pe broadcast over batch) ----------
__global__ __launch_bounds__(256) void add_pe_k(const float* __restrict__ x, const float* __restrict__ pe,
                                                float* __restrict__ h) {
  long i = (long)blockIdx.x * 256 + threadIdx.x;
  long nd = i % ((long)Nn * Dd);
  h[i] = x[i] + pe[nd];
}

// ---------- LayerNorm; OBF=1 writes bf16 output ----------
template<int OBF>
__global__ __launch_bounds__(256) void ln_kernel(const float* __restrict__ X,
                                                 const float* __restrict__ w, const float* __restrict__ b,
                                                 void* __restrict__ Y) {
  __shared__ float smem[4];
  int row = blockIdx.x, tid = threadIdx.x;
  const float* x = X + (size_t)row * Dd;
  float v[3];
  for (int j = 0; j < 3; ++j) v[j] = x[tid + j * 256];
  float s = v[0] + v[1] + v[2];
  s = block_reduce_sum(s, smem);
  float mean = s * (1.f / 768.f);
  float q = 0.f;
  for (int j = 0; j < 3; ++j) { float d = v[j] - mean; q += d * d; }
  q = block_reduce_sum(q, smem);
  float inv = rsqrtf(q * (1.f / 768.f) + 1e-5f);
  for (int j = 0; j < 3; ++j) {
    int c = tid + j * 256;
    float r = (v[j] - mean) * inv * w[c] + b[c];
    if (OBF) ((__bf16*)Y)[(size_t)row * Dd + c] = (__bf16)r;
    else     ((float*)Y)[(size_t)row * Dd + c] = r;
  }
}

// ---------- residual + LayerNorm: v = h + p0 + p1 + bias; Y = LN(v).
// HRES=0 (post-LN attn stage): h <- LN(v).  HRES=1 (ff2 stage / final): h <- v.
template<int OBF, int HRES>
__global__ __launch_bounds__(256) void res_ln_kernel(float* __restrict__ H,
                                                     const float* __restrict__ P0, const float* __restrict__ P1,
                                                     const float* __restrict__ pb,
                                                     const float* __restrict__ w, const float* __restrict__ b,
                                                     void* __restrict__ Y) {
  __shared__ float smem[4];
  int row = blockIdx.x, tid = threadIdx.x;
  float* x  = H  + (size_t)row * Dd;
  const float* p0 = P0 + (size_t)row * Dd;
  const float* p1 = P1 + (size_t)row * Dd;
  float v[3];
  for (int j = 0; j < 3; ++j) {
    int c = tid + j * 256;
    v[j] = x[c] + (p0[c] + p1[c] + pb[c]);
  }
  float s = v[0] + v[1] + v[2];
  s = block_reduce_sum(s, smem);
  float mean = s * (1.f / 768.f);
  float q = 0.f;
  for (int j = 0; j < 3; ++j) { float d = v[j] - mean; q += d * d; }
  q = block_reduce_sum(q, smem);
  float inv = rsqrtf(q * (1.f / 768.f) + 1e-5f);
  for (int j = 0; j < 3; ++j) {
    int c = tid + j * 256;
    float r = (v[j] - mean) * inv * w[c] + b[c];
    x[c] = HRES ? v[j] : r;
    if (OBF) ((__bf16*)Y)[(size_t)row * Dd + c] = (__bf16)r;
    else     ((float*)Y)[(size_t)row * Dd + c] = r;
  }
}

// ---------- 128xBN MFMA GEMM: A bf16 direct, B bf16 (pre-converted), reg prefetch,
// ---------- XCD chunk swizzle, optional split-K, optional bf16 output ----------
// BN=64: FN=2 (8 MFMA/wave/step).  BN=128: FN=4 (16 MFMA/wave/step, LDS 40KB).
template<int BN, int EPI, int OBF>
__global__ __launch_bounds__(256) void gemm128(
    const __bf16* __restrict__ Ap, long lda,
    const __bf16* __restrict__ Bp, long ldb,
    const float* __restrict__ bias,
    void* __restrict__ Cp, long ldc,
    int Ksize, long czs)
{
  constexpr int FN = BN / 32;
  constexpr int KB = BN / 8;
  int tid = threadIdx.x;

  int nwg2 = gridDim.x * gridDim.y;
  int bid = blockIdx.y * gridDim.x + blockIdx.x;
  int swz = (bid & 7) * (nwg2 >> 3) + (bid >> 3);
  int bx = swz % gridDim.x, by = swz / gridDim.x;
  int m0 = by * 128, n0 = bx * BN;
  int z = blockIdx.z;

  const __bf16* Aq = Ap + (long)z * Ksize;
  const __bf16* Bq = Bp + (long)z * Ksize * ldb;

  __shared__ __align__(16) __bf16 Ah[128][40];
  __shared__ __align__(16) __bf16 Bh[BN][40];

  f32x4 acc[4][FN];
  #pragma unroll
  for (int i = 0; i < 4; ++i)
    #pragma unroll
    for (int j = 0; j < FN; ++j)
      #pragma unroll
      for (int k = 0; k < 4; ++k) acc[i][j][k] = 0.f;

  int lane = tid & 63;
  int w = tid >> 6;
  int WR = (w >> 1) * 64, WC = (w & 1) * (BN / 2);
  int fr = lane & 15, kg = lane >> 4;

  const int ar = tid >> 1, acs = (tid & 1) * 16;
  const int bn = tid % BN;
  const int kb = (tid / BN) * KB;

  const __bf16* Abase = Aq + (long)(m0 + ar) * lda + acs;
  const __bf16* Bbase = Bq + (long)kb * ldb + (n0 + bn);

  bf16x8 pa0, pa1;
  __bf16 pbh[KB];
  {
    pa0 = *reinterpret_cast<const bf16x8*>(Abase);
    pa1 = *reinterpret_cast<const bf16x8*>(Abase + 8);
    #pragma unroll
    for (int j = 0; j < KB; ++j) pbh[j] = Bbase[(long)j * ldb];
  }

  for (int k0 = 0; k0 < Ksize; k0 += 32) {
    __syncthreads();
    {
      *reinterpret_cast<bf16x8*>(&Ah[ar][acs]) = pa0;
      *reinterpret_cast<bf16x8*>(&Ah[ar][acs + 8]) = pa1;
      #pragma unroll
      for (int g8 = 0; g8 < KB / 8; ++g8)
        *reinterpret_cast<bf16x8*>(&Bh[bn][kb + g8 * 8]) = *reinterpret_cast<bf16x8*>(&pbh[g8 * 8]);
    }
    __syncthreads();

    if (k0 + 32 < Ksize) {
      const __bf16* As = Abase + (k0 + 32);
      pa0 = *reinterpret_cast<const bf16x8*>(As);
      pa1 = *reinterpret_cast<const bf16x8*>(As + 8);
      const __bf16* Bs = Bbase + (long)(k0 + 32) * ldb;
      #pragma unroll
      for (int j = 0; j < KB; ++j) pbh[j] = Bs[(long)j * ldb];
    }

    bf16x8 ah[4], bh[FN];
    #pragma unroll
    for (int fm = 0; fm < 4; ++fm)
      ah[fm] = *reinterpret_cast<const bf16x8*>(&Ah[WR + fm * 16 + fr][kg * 8]);
    #pragma unroll
    for (int fn = 0; fn < FN; ++fn)
      bh[fn] = *reinterpret_cast<const bf16x8*>(&Bh[WC + fn * 16 + fr][kg * 8]);
    #pragma unroll
    for (int fm = 0; fm < 4; ++fm)
      #pragma unroll
      for (int fn = 0; fn < FN; ++fn)
        acc[fm][fn] = __builtin_amdgcn_mfma_f32_16x16x32_bf16(ah[fm], bh[fn], acc[fm][fn], 0, 0, 0);
  }

  #pragma unroll
  for (int fm = 0; fm < 4; ++fm)
    #pragma unroll
    for (int fn = 0; fn < FN; ++fn)
      #pragma unroll
      for (int i = 0; i < 4; ++i) {
        int rowg = m0 + WR + fm * 16 + kg * 4 + i;
        int coln = n0 + WC + fn * 16 + fr;
        float v = acc[fm][fn][i];
        if (EPI >= 1) v += bias[coln];
        if (EPI == 2) v = 0.5f * v * (1.f + erff(v * 0.70710678118654752f));
        long ci = (long)z * czs + (long)rowg * ldc + coln;
        if (OBF) ((__bf16*)Cp)[ci] = (__bf16)v;
        else     ((float*)Cp)[ci] = v;
      }
}

// ---------- MFMA flash attention, KV-split x4, bf16 qkv input, bf16 unnormalized partials ----------
__global__ __launch_bounds__(256) void flash_attn_split(const __bf16* __restrict__ qkvb,
                                                        const void* __restrict__ mraw,
                                                        const int* __restrict__ flagp,
                                                        __bf16* __restrict__ pf,   // NS x Mm*Dd bf16
                                                        float2* __restrict__ ml) {
  __shared__ __align__(16) __bf16 Qs[64][72];
  __shared__ __align__(16) __bf16 Ks[64][72];
  __shared__ __align__(16) __bf16 Vt[64][66];  // V transposed: [d][key]
  __shared__ __align__(16) __bf16 Ps[64][72];
  __shared__ float kmf[64];
  __shared__ float qmf[64];

  int s = blockIdx.z & (NS - 1), b = blockIdx.z >> 2;
  int hh = blockIdx.y;
  int q0 = blockIdx.x * 64;
  int tid = threadIdx.x, lane = tid & 63, w = tid >> 6;
  int flag = *flagp;
  int fr = lane & 15, kg = lane >> 4;

  const int sr = tid >> 2;
  const int sc = (tid & 3) * 16;

  {
    const __bf16* Qsrc = qkvb + ((long)(b * Nn + q0 + sr)) * (3 * Dd) + hh * HDd + sc;
    *reinterpret_cast<bf16x8*>(&Qs[sr][sc])     = *reinterpret_cast<const bf16x8*>(Qsrc);
    *reinterpret_cast<bf16x8*>(&Qs[sr][sc + 8]) = *reinterpret_cast<const bf16x8*>(Qsrc + 8);
    if (tid < 64) qmf[tid] = mask_at(mraw, flag, b * Nn + q0 + tid) ? 1.f : 0.f;
  }
  __syncthreads();

  float qm[4];
  #pragma unroll
  for (int i = 0; i < 4; ++i) qm[i] = qmf[16 * w + kg * 4 + i];

  bf16x8 qa[2];
  #pragma unroll
  for (int ks = 0; ks < 2; ++ks)
    qa[ks] = *reinterpret_cast<const bf16x8*>(&Qs[16 * w + fr][ks * 32 + kg * 8]);

  float mrow[4], lrow[4];
  f32x4 accO[4];
  #pragma unroll
  for (int i = 0; i < 4; ++i) { mrow[i] = -INFINITY; lrow[i] = 0.f; }
  #pragma unroll
  for (int t = 0; t < 4; ++t)
    for (int i = 0; i < 4; ++i) accO[t][i] = 0.f;

  const int jbeg = s * (Nn / NS), jend = jbeg + (Nn / NS);

  bf16x8 rk0, rk1, rv0, rv1;
  {
    const __bf16* Ksrc = qkvb + ((long)(b * Nn + jbeg + sr)) * (3 * Dd) + Dd + hh * HDd + sc;
    const __bf16* Vsrc = Ksrc + Dd;
    rk0 = *reinterpret_cast<const bf16x8*>(Ksrc);
    rk1 = *reinterpret_cast<const bf16x8*>(Ksrc + 8);
    rv0 = *reinterpret_cast<const bf16x8*>(Vsrc);
    rv1 = *reinterpret_cast<const bf16x8*>(Vsrc + 8);
  }

  for (int j0 = jbeg; j0 < jend; j0 += 64) {
    __syncthreads();
    {
      *reinterpret_cast<bf16x8*>(&Ks[sr][sc])     = rk0;
      *reinterpret_cast<bf16x8*>(&Ks[sr][sc + 8]) = rk1;
      #pragma unroll
      for (int j = 0; j < 8; ++j) {
        Vt[sc + j][sr]     = rv0[j];
        Vt[sc + 8 + j][sr] = rv1[j];
      }
      if (tid < 64) kmf[tid] = mask_at(mraw, flag, b * Nn + j0 + tid) ? 1.f : 0.f;
    }
    __syncthreads();

    if (j0 + 64 < jend) {
      const __bf16* Ksrc = qkvb + ((long)(b * Nn + j0 + 64 + sr)) * (3 * Dd) + Dd + hh * HDd + sc;
      const __bf16* Vsrc = Ksrc + Dd;
      rk0 = *reinterpret_cast<const bf16x8*>(Ksrc);
      rk1 = *reinterpret_cast<const bf16x8*>(Ksrc + 8);
      rv0 = *reinterpret_cast<const bf16x8*>(Vsrc);
      rv1 = *reinterpret_cast<const bf16x8*>(Vsrc + 8);
    }

    f32x4 sacc[4];
    #pragma unroll
    for (int t = 0; t < 4; ++t)
      for (int i = 0; i < 4; ++i) sacc[t][i] = 0.f;
    #pragma unroll
    for (int ks = 0; ks < 2; ++ks) {
      #pragma unroll
      for (int t = 0; t < 4; ++t) {
        bf16x8 bh = *reinterpret_cast<const bf16x8*>(&Ks[16 * t + fr][ks * 32 + kg * 8]);
        sacc[t] = __builtin_amdgcn_mfma_f32_16x16x32_bf16(qa[ks], bh, sacc[t], 0, 0, 0);
      }
    }

    float sv[4][4];
    float mt[4] = {-INFINITY, -INFINITY, -INFINITY, -INFINITY};
    #pragma unroll
    for (int t = 0; t < 4; ++t) {
      float km = kmf[16 * t + fr];
      #pragma unroll
      for (int i = 0; i < 4; ++i) {
        float sx = (km > 0.f && qm[i] > 0.f) ? sacc[t][i] * 0.125f : NEGF;
        sv[t][i] = sx;
        mt[i] = fmaxf(mt[i], sx);
      }
    }
    #pragma unroll
    for (int off = 8; off; off >>= 1)
      #pragma unroll
      for (int i = 0; i < 4; ++i) mt[i] = fmaxf(mt[i], __shfl_xor(mt[i], off));

    float r[4], psum[4];
    #pragma unroll
    for (int i = 0; i < 4; ++i) {
      float mn = fmaxf(mrow[i], mt[i]);
      r[i] = __expf(mrow[i] - mn);
      mrow[i] = mn;
      psum[i] = 0.f;
    }
    #pragma unroll
    for (int t = 0; t < 4; ++t) {
      #pragma unroll
      for (int i = 0; i < 4; ++i) {
        float p = __expf(sv[t][i] - mrow[i]);
        psum[i] += p;
        Ps[16 * w + kg * 4 + i][16 * t + fr] = (__bf16)p;
      }
    }
    #pragma unroll
    for (int off = 8; off; off >>= 1)
      #pragma unroll
      for (int i = 0; i < 4; ++i) psum[i] += __shfl_xor(psum[i], off);
    #pragma unroll
    for (int i = 0; i < 4; ++i) lrow[i] = lrow[i] * r[i] + psum[i];
    #pragma unroll
    for (int t = 0; t < 4; ++t)
      #pragma unroll
      for (int i = 0; i < 4; ++i) accO[t][i] *= r[i];

    __syncthreads();

    #pragma unroll
    for (int ks = 0; ks < 2; ++ks) {
      bf16x8 pa = *reinterpret_cast<const bf16x8*>(&Ps[16 * w + fr][ks * 32 + kg * 8]);
      #pragma unroll
      for (int t2 = 0; t2 < 4; ++t2) {
        bf16x8 vb = *reinterpret_cast<const bf16x8*>(&Vt[16 * t2 + fr][ks * 32 + kg * 8]);
        accO[t2] = __builtin_amdgcn_mfma_f32_16x16x32_bf16(pa, vb, accO[t2], 0, 0, 0);
      }
    }
  }

  __bf16* op = pf + (long)s * Mm * Dd;
  #pragma unroll
  for (int t2 = 0; t2 < 4; ++t2)
    #pragma unroll
    for (int i = 0; i < 4; ++i) {
      int qrow = q0 + 16 * w + kg * 4 + i;
      int col = 16 * t2 + fr;
      op[((long)(b * Nn + qrow)) * Dd + hh * HDd + col] = (__bf16)accO[t2][i];  // unnormalized bf16
    }
  if (fr == 0) {
    #pragma unroll
    for (int i = 0; i < 4; ++i) {
      int qrow = q0 + 16 * w + kg * 4 + i;
      ml[((long)(s * Bb + b) * Hh + hh) * Nn + qrow] = make_float2(mrow[i], lrow[i]);
    }
  }
}

// ---------- combine NS KV-splits -> bf16 attn output ----------
__global__ __launch_bounds__(256) void flash_combine4(const __bf16* __restrict__ pf,
                                                      const float2* __restrict__ ml, __bf16* __restrict__ ob) {
  long i4 = (long)blockIdx.x * 256 + threadIdx.x;
  long i = i4 * 4;
  int d = (int)(i % Dd);
  long row = i / Dd;
  int b = (int)(row >> 10), n = (int)(row & (Nn - 1));
  int hh = d >> 6;
  float2 mls[NS];
  float M = -INFINITY;
  #pragma unroll
  for (int s = 0; s < NS; ++s) {
    mls[s] = ml[((long)(s * Bb + b) * Hh + hh) * Nn + n];
    M = fmaxf(M, mls[s].x);
  }
  float wgt[NS], denom = 0.f;
  #pragma unroll
  for (int s = 0; s < NS; ++s) {
    wgt[s] = __expf(mls[s].x - M);
    denom += wgt[s] * mls[s].y;
  }
  float inv = 1.f / denom;
  float acc[4] = {0.f, 0.f, 0.f, 0.f};
  #pragma unroll
  for (int s = 0; s < NS; ++s) {
    bf16x4 v = reinterpret_cast<const bf16x4*>(pf + (long)s * Mm * Dd)[i4];
    #pragma unroll
    for (int j = 0; j < 4; ++j) acc[j] += wgt[s] * (float)v[j];
  }
  bf16x4 r;
  #pragma unroll
  for (int j = 0; j < 4; ++j) r[j] = (__bf16)(acc[j] * inv);
  *reinterpret_cast<bf16x4*>(&ob[i]) = r;
}

// ---------- seq-pool ----------
__global__ __launch_bounds__(256) void pool_score(const float* __restrict__ hn, const float* __restrict__ pw,
                                                  const float* __restrict__ pb, float* __restrict__ s) {
  __shared__ float smem[4];
  int row = blockIdx.x, tid = threadIdx.x;
  const float* x = hn + (size_t)row * Dd;
  float acc = 0.f;
  for (int j = 0; j < 3; ++j) { int c = tid + j * 256; acc += x[c] * pw[c]; }
  acc = block_reduce_sum(acc, smem);
  if (tid == 0) s[row] = acc + pb[0];
}

__global__ __launch_bounds__(256) void pool_softmax(const float* __restrict__ s, float* __restrict__ w) {
  __shared__ float smem[4];
  int b = blockIdx.x, tid = threadIdx.x;
  const float* x = s + b * Nn;
  float v[4];
  for (int j = 0; j < 4; ++j) v[j] = x[tid * 4 + j];
  float mx = fmaxf(fmaxf(v[0], v[1]), fmaxf(v[2], v[3]));
  mx = block_reduce_max(mx, smem);
  float e[4], sum = 0.f;
  for (int j = 0; j < 4; ++j) { e[j] = expf(v[j] - mx); sum += e[j]; }
  sum = block_reduce_sum(sum, smem);
  float inv = 1.f / sum;
  for (int j = 0; j < 4; ++j) w[b * Nn + tid * 4 + j] = e[j] * inv;
}

// stage 1: partial sums over 128-token chunks. grid (Dd/256, 8, Bb), block 256.
__global__ __launch_bounds__(256) void pool_reduce1(const float* __restrict__ hn, const float* __restrict__ w,
                                                    float* __restrict__ part) {
  int d = blockIdx.x * 256 + threadIdx.x;
  int ch = blockIdx.y, b = blockIdx.z;
  int n0 = ch * 128;
  float a0 = 0.f, a1 = 0.f;
  for (int n = n0; n < n0 + 128; n += 2) {
    a0 = fmaf(w[b * Nn + n],     hn[((size_t)(b * Nn + n))     * Dd + d], a0);
    a1 = fmaf(w[b * Nn + n + 1], hn[((size_t)(b * Nn + n + 1)) * Dd + d], a1);
  }
  part[((size_t)(b * 8 + ch)) * Dd + d] = a0 + a1;
}

// stage 2: sum 8 partials. grid (Dd/256, Bb), block 256.
__global__ __launch_bounds__(256) void pool_reduce2(const float* __restrict__ part, float* __restrict__ pooled) {
  int d = blockIdx.x * 256 + threadIdx.x;
  int b = blockIdx.y;
  float s = 0.f;
  #pragma unroll
  for (int ch = 0; ch < 8; ++ch) s += part[((size_t)(b * 8 + ch)) * Dd + d];
  pooled[b * Dd + d] = s;
}

// fc: one class per thread, coalesced over c. grid (4, Bb), block 256.
__global__ __launch_bounds__(256) void fc_kernel(const float* __restrict__ pooled, const float* __restrict__ fw,
                                                 const float* __restrict__ fb, float* __restrict__ out) {
  __shared__ float p[768];
  int b = blockIdx.y, tid = threadIdx.x;
  for (int j = 0; j < 3; ++j) p[tid + j * 256] = pooled[b * Dd + tid + j * 256];
  __syncthreads();
  int c = blockIdx.x * 256 + tid;
  if (c < NCc) {
    float a0 = 0.f, a1 = 0.f, a2 = 0.f, a3 = 0.f;
    #pragma unroll 4
    for (int d = 0; d < Dd; d += 4) {
      a0 = fmaf(p[d],     fw[(size_t)d       * NCc + c], a0);
      a1 = fmaf(p[d + 1], fw[(size_t)(d + 1) * NCc + c], a1);
      a2 = fmaf(p[d + 2], fw[(size_t)(d + 2) * NCc + c], a2);
      a3 = fmaf(p[d + 3], fw[(size_t)(d + 3) * NCc + c], a3);
    }
    out[b * NCc + c] = fb[c] + ((a0 + a1) + (a2 + a3));
  }
}

extern "C" void kernel_launch(void* const* d_in, const int* in_sizes, int n_in,
                              void* d_out, int out_size, void* d_ws, size_t ws_size,
                              hipStream_t stream) {
  const float* x      = (const float*)d_in[0];
  const void*  mask   = d_in[1];
  const float* pe     = (const float*)d_in[2];
  const float* ln0_w  = (const float*)d_in[3];
  const float* ln0_b  = (const float*)d_in[4];
  const float* qkv_w  = (const float*)d_in[5];
  const float* proj_w = (const float*)d_in[6];
  const float* proj_b = (const float*)d_in[7];
  const float* ln1_w  = (const float*)d_in[8];
  const float* ln1_b  = (const float*)d_in[9];
  const float* ff1_w  = (const float*)d_in[10];
  const float* ff1_b  = (const float*)d_in[11];
  const float* ff2_w  = (const float*)d_in[12];
  const float* ff2_b  = (const float*)d_in[13];
  const float* norm_w = (const float*)d_in[14];
  const float* norm_b = (const float*)d_in[15];
  const float* pool_w = (const float*)d_in[16];
  const float* pool_b = (const float*)d_in[17];
  const float* fc_w   = (const float*)d_in[18];
  const float* fc_b   = (const float*)d_in[19];
  float* out = (float*)d_out;

  float* ws = (float*)d_ws;
  float*  h     = ws;                            // Mm*Dd f32 (residual)
  float*  s0    = h + (long)Mm * Dd;             // Mm*Dd f32 scratch (also: NS bf16 flash partials)
  float*  s1    = s0 + (long)Mm * Dd;            // Mm*Dd f32 scratch
  __bf16* qkvb  = (__bf16*)(s1 + (long)Mm * Dd); // Mm*3*Dd bf16
  __bf16* ob    = qkvb + (long)Mm * 3 * Dd;      // Mm*Dd bf16 (attn out)
  __bf16* yb    = ob + (long)Mm * Dd;            // Mm*Dd bf16 (ln out)

  __bf16* pflash = (__bf16*)s0;                  // NS x Mm*Dd bf16 == s0+s1 region exactly

  const bool bigws = ws_size >= (size_t)54 * 1024 * 1024;
  __bf16* wreg = yb + (long)Mm * Dd;
  __bf16 *wq, *wp, *w1, *w2;
  __bf16* wend;
  if (bigws) {
    wq = wreg;
    wp = wq + (long)Dd * 3 * Dd;
    w1 = wp + (long)Dd * Dd;
    w2 = w1 + (long)Dd * FFf;
    wend = w2 + (long)FFf * Dd;
  } else {
    wq = wp = w1 = w2 = wreg;
    wend = wreg + (long)Dd * FFf;
  }
  float*  tail  = (float*)wend;
  float*  spool  = tail;                         // Mm
  float*  wpool  = spool + Mm;                   // Mm
  float*  pooled = wpool + Mm;                   // Bb*Dd
  float*  ppart  = pooled + Bb * Dd;             // Bb*8*Dd
  float*  mlbuf  = ppart + (long)Bb * 8 * Dd;    // NS*Bb*Hh*Nn float2
  int*    mflag  = (int*)(mlbuf + (long)2 * NS * Bb * Hh * Nn);
  __bf16* gb = qkvb;     // alias: gelu out Mm*FFf bf16 == qkvb+ob region exactly
  float*  hn = s0;       // final LN out (after loop; s0 free)

  const int n8_qkv  = Dd * 3 * Dd / 8;
  const int n8_proj = Dd * Dd / 8;
  const int n8_ff   = Dd * FFf / 8;
  const int n8_all  = n8_qkv + n8_proj + 2 * n8_ff;

  detect_mask<<<1, 256, 0, stream>>>((const unsigned char*)mask, mflag);
  add_pe_k<<<(Mm * Dd) / 256, 256, 0, stream>>>(x, pe, h);
  ln_kernel<1><<<Mm, 256, 0, stream>>>(h, ln0_w, ln0_b, yb);

  for (int l = 0; l < NLl; ++l) {
    if (bigws) {
      cvt_w4<<<(n8_all + 255) / 256, 256, 0, stream>>>(
          qkv_w + (long)l * Dd * 3 * Dd, proj_w + (long)l * Dd * Dd,
          ff1_w + (long)l * Dd * FFf, ff2_w + (long)l * FFf * Dd,
          wq, wp, w1, w2);
    } else {
      cvt_w<<<(n8_qkv + 255) / 256, 256, 0, stream>>>(qkv_w + (long)l * Dd * 3 * Dd, wq, n8_qkv);
    }

    // qkv: BN=128 (FN=4, 16 MFMA/wave/step)
    gemm128<128,0,1><<<dim3(3 * Dd / 128, Mm / 128, 1), 256, 0, stream>>>(
        yb, Dd, wq, 3 * Dd, nullptr, qkvb, 3 * Dd, Dd, 0);

    // fused attention, KV-split x4: bf16 partials -> pflash; combine -> ob (bf16)
    flash_attn_split<<<dim3(Nn / 64, Hh, Bb * NS), 256, 0, stream>>>(
        qkvb, mask, mflag, pflash, (float2*)mlbuf);
    flash_combine4<<<(Mm * Dd / 4) / 256, 256, 0, stream>>>(pflash, (const float2*)mlbuf, ob);

    if (!bigws)
      cvt_w<<<(n8_proj + 255) / 256, 256, 0, stream>>>(proj_w + (long)l * Dd * Dd, wp, n8_proj);
    // proj split-K x2 -> s0, s1 (flash partials dead after combine)
    gemm128<64,0,0><<<dim3(Dd / 64, Mm / 128, 2), 256, 0, stream>>>(
        ob, Dd, wp, Dd, nullptr, s0, Dd, Dd / 2, (long)(s1 - s0));

    res_ln_kernel<1,0><<<Mm, 256, 0, stream>>>(h, s0, s1, proj_b + l * Dd,
                                               ln1_w + l * Dd, ln1_b + l * Dd, yb);

    if (!bigws)
      cvt_w<<<(n8_ff + 255) / 256, 256, 0, stream>>>(ff1_w + (long)l * Dd * FFf, w1, n8_ff);
    // ff1: BN=128 (FN=4)
    gemm128<128,2,1><<<dim3(FFf / 128, Mm / 128, 1), 256, 0, stream>>>(
        yb, Dd, w1, FFf, ff1_b + l * FFf, gb, FFf, Dd, 0);

    if (!bigws)
      cvt_w<<<(n8_ff + 255) / 256, 256, 0, stream>>>(ff2_w + (long)l * FFf * Dd, w2, n8_ff);
    gemm128<64,0,0><<<dim3(Dd / 64, Mm / 128, 2), 256, 0, stream>>>(
        gb, FFf, w2, Dd, nullptr, s0, Dd, FFf / 2, (long)(s1 - s0));

    if (l + 1 < NLl) {
      res_ln_kernel<1,1><<<Mm, 256, 0, stream>>>(h, s0, s1, ff2_b + l * Dd,
                                                 ln0_w + (l + 1) * Dd, ln0_b + (l + 1) * Dd, yb);
    } else {
      res_ln_kernel<0,1><<<Mm, 256, 0, stream>>>(h, s0, s1, ff2_b + l * Dd,
                                                 norm_w, norm_b, hn);
    }
  }

  pool_score<<<Mm, 256, 0, stream>>>(hn, pool_w, pool_b, spool);
  pool_softmax<<<Bb, 256, 0, stream>>>(spool, wpool);
  pool_reduce1<<<dim3(Dd / 256, 8, Bb), 256, 0, stream>>>(hn, wpool, ppart);
  pool_reduce2<<<dim3(Dd / 256, Bb), 256, 0, stream>>>(ppart, pooled);
  fc_kernel<<<dim3(4, Bb), 256, 0, stream>>>(pooled, fc_w, fc_b, out);
}

// Round 22
// 1967.315 us; speedup vs baseline: 1.0608x; 1.0608x over previous
//
#include <hip/hip_runtime.h>
#include <hip/hip_bf16.h>
#include <cfloat>
#include <cmath>

typedef __bf16 bf16x8 __attribute__((ext_vector_type(8)));
typedef __bf16 bf16x4 __attribute__((ext_vector_type(4)));
typedef float  f32x4  __attribute__((ext_vector_type(4)));

static constexpr int Bb = 2, Nn = 1024, Dd = 768, Hh = 12, HDd = 64, FFf = 3072, NLl = 12, NCc = 1000;
static constexpr int Mm = Bb * Nn; // 2048
static constexpr float NEGF = -3.402823466e38f;

// ---------- reductions (256-thread blocks = 4 waves) ----------
__device__ __forceinline__ float block_reduce_sum(float v, volatile float* smem) {
  for (int o = 32; o; o >>= 1) v += __shfl_down(v, o);
  int lane = threadIdx.x & 63, w = threadIdx.x >> 6;
  __syncthreads();
  if (lane == 0) smem[w] = v;
  __syncthreads();
  return smem[0] + smem[1] + smem[2] + smem[3];
}

__device__ __forceinline__ float block_reduce_max(float v, volatile float* smem) {
  for (int o = 32; o; o >>= 1) v = fmaxf(v, __shfl_down(v, o));
  int lane = threadIdx.x & 63, w = threadIdx.x >> 6;
  __syncthreads();
  if (lane == 0) smem[w] = v;
  __syncthreads();
  return fmaxf(fmaxf(smem[0], smem[1]), fmaxf(smem[2], smem[3]));
}

// ---------- mask dtype detection: 0=int32 1=bytes 2=f32 3=int64 4=bf16 ----------
__global__ void detect_mask(const unsigned char* __restrict__ m, int* __restrict__ flag) {
  __shared__ int s_nz1, s_nz2, s_nz3, s_nz84, s_pv;
  int tid = threadIdx.x;
  if (tid == 0) { s_nz1 = 0; s_nz2 = 0; s_nz3 = 0; s_nz84 = 0; s_pv = 0; }
  __syncthreads();
  int nz1 = 0, nz2 = 0, nz3 = 0, nz84 = 0, pv = 0;
  for (int i = tid; i < 2048; i += 256) {
    unsigned char v = m[i];
    if (v) {
      int p4 = i & 3;
      if (p4 == 1) nz1 = 1;
      if (p4 == 2) nz2 = 1;
      if (p4 == 3) nz3 = 1;
      if ((i & 7) == 4) nz84 = 1;
      if ((i & 1) == 0) { if (v != 0x80) pv = 1; }
      else              { if (v != 0x3f) pv = 1; }
    }
  }
  if (nz1)  atomicOr(&s_nz1, 1);
  if (nz2)  atomicOr(&s_nz2, 1);
  if (nz3)  atomicOr(&s_nz3, 1);
  if (nz84) atomicOr(&s_nz84, 1);
  if (pv)   atomicOr(&s_pv, 1);
  __syncthreads();
  if (tid == 0) {
    int f;
    if (!s_nz1 && !s_nz2 && !s_nz3) f = s_nz84 ? 0 : 3;
    else if (!s_pv)                 f = s_nz1 ? 4 : 2;
    else                            f = 1;
    *flag = f;
  }
}

__device__ __forceinline__ bool mask_at(const void* mraw, int flag, int idx) {
  switch (flag) {
    case 0:  return ((const int*)mraw)[idx] != 0;
    case 1:  return ((const unsigned char*)mraw)[idx] != 0;
    case 2:  return ((const float*)mraw)[idx] != 0.f;
    case 3:  return ((const long long*)mraw)[idx] != 0;
    default: return ((const unsigned short*)mraw)[idx] != 0;
  }
}

// ---------- weight f32 -> bf16 (8 elems/thread) ----------
__device__ __forceinline__ void cvt8_store(const float* __restrict__ s, __bf16* __restrict__ d, int j) {
  float4 f0 = reinterpret_cast<const float4*>(s)[j * 2];
  float4 f1 = reinterpret_cast<const float4*>(s)[j * 2 + 1];
  bf16x8 r;
  r[0] = (__bf16)f0.x; r[1] = (__bf16)f0.y; r[2] = (__bf16)f0.z; r[3] = (__bf16)f0.w;
  r[4] = (__bf16)f1.x; r[5] = (__bf16)f1.y; r[6] = (__bf16)f1.z; r[7] = (__bf16)f1.w;
  reinterpret_cast<bf16x8*>(d)[j] = r;
}

__global__ __launch_bounds__(256) void cvt_w(const float* __restrict__ src, __bf16* __restrict__ dst, int n8) {
  int i = blockIdx.x * 256 + threadIdx.x;
  if (i < n8) cvt8_store(src, dst, i);
}

// one launch converts all 4 per-layer weights (qkv, proj, ff1, ff2)
__global__ __launch_bounds__(256) void cvt_w4(const float* __restrict__ sq, const float* __restrict__ sp,
                                              const float* __restrict__ s1, const float* __restrict__ s2,
                                              __bf16* __restrict__ dq, __bf16* __restrict__ dp,
                                              __bf16* __restrict__ d1, __bf16* __restrict__ d2) {
  const int N0 = Dd * 3 * Dd / 8, N1 = Dd * Dd / 8, N2 = Dd * FFf / 8, N3 = FFf * Dd / 8;
  int i = blockIdx.x * 256 + threadIdx.x;
  if (i < N0)                    cvt8_store(sq, dq, i);
  else if (i < N0 + N1)          cvt8_store(sp, dp, i - N0);
  else if (i < N0 + N1 + N2)     cvt8_store(s1, d1, i - N0 - N1);
  else if (i < N0 + N1 + N2 + N3) cvt8_store(s2, d2, i - N0 - N1 - N2);
}

// ---------- h = x + pe (pe broadcast over batch) ----------
__global__ __launch_bounds__(256) void add_pe_k(const float* __restrict__ x, const float* __restrict__ pe,
                                                float* __restrict__ h) {
  long i = (long)blockIdx.x * 256 + threadIdx.x;
  long nd = i % ((long)Nn * Dd);
  h[i] = x[i] + pe[nd];
}

// ---------- LayerNorm; OBF=1 writes bf16 output ----------
template<int OBF>
__global__ __launch_bounds__(256) void ln_kernel(const float* __restrict__ X,
                                                 const float* __restrict__ w, const float* __restrict__ b,
                                                 void* __restrict__ Y) {
  __shared__ float smem[4];
  int row = blockIdx.x, tid = threadIdx.x;
  const float* x = X + (size_t)row * Dd;
  float v[3];
  for (int j = 0; j < 3; ++j) v[j] = x[tid + j * 256];
  float s = v[0] + v[1] + v[2];
  s = block_reduce_sum(s, smem);
  float mean = s * (1.f / 768.f);
  float q = 0.f;
  for (int j = 0; j < 3; ++j) { float d = v[j] - mean; q += d * d; }
  q = block_reduce_sum(q, smem);
  float inv = rsqrtf(q * (1.f / 768.f) + 1e-5f);
  for (int j = 0; j < 3; ++j) {
    int c = tid + j * 256;
    float r = (v[j] - mean) * inv * w[c] + b[c];
    if (OBF) ((__bf16*)Y)[(size_t)row * Dd + c] = (__bf16)r;
    else     ((float*)Y)[(size_t)row * Dd + c] = r;
  }
}

// ---------- residual + LayerNorm: v = h + p0 + p1 + bias; Y = LN(v).
// HRES=0 (post-LN attn stage): h <- LN(v).  HRES=1 (ff2 stage / final): h <- v.
template<int OBF, int HRES>
__global__ __launch_bounds__(256) void res_ln_kernel(float* __restrict__ H,
                                                     const float* __restrict__ P0, const float* __restrict__ P1,
                                                     const float* __restrict__ pb,
                                                     const float* __restrict__ w, const float* __restrict__ b,
                                                     void* __restrict__ Y) {
  __shared__ float smem[4];
  int row = blockIdx.x, tid = threadIdx.x;
  float* x  = H  + (size_t)row * Dd;
  const float* p0 = P0 + (size_t)row * Dd;
  const float* p1 = P1 + (size_t)row * Dd;
  float v[3];
  for (int j = 0; j < 3; ++j) {
    int c = tid + j * 256;
    v[j] = x[c] + (p0[c] + p1[c] + pb[c]);
  }
  float s = v[0] + v[1] + v[2];
  s = block_reduce_sum(s, smem);
  float mean = s * (1.f / 768.f);
  float q = 0.f;
  for (int j = 0; j < 3; ++j) { float d = v[j] - mean; q += d * d; }
  q = block_reduce_sum(q, smem);
  float inv = rsqrtf(q * (1.f / 768.f) + 1e-5f);
  for (int j = 0; j < 3; ++j) {
    int c = tid + j * 256;
    float r = (v[j] - mean) * inv * w[c] + b[c];
    x[c] = HRES ? v[j] : r;
    if (OBF) ((__bf16*)Y)[(size_t)row * Dd + c] = (__bf16)r;
    else     ((float*)Y)[(size_t)row * Dd + c] = r;
  }
}

// ---------- 128x64 MFMA GEMM: A bf16 direct, B bf16 (pre-converted), reg prefetch,
// ---------- XCD chunk swizzle, optional split-K, optional bf16 output ----------
template<int BN, int EPI, int OBF>
__global__ __launch_bounds__(256) void gemm128(
    const __bf16* __restrict__ Ap, long lda,
    const __bf16* __restrict__ Bp, long ldb,
    const float* __restrict__ bias,
    void* __restrict__ Cp, long ldc,
    int Ksize, long czs)
{
  constexpr int FN = BN / 32;
  constexpr int KB = BN / 8;
  int tid = threadIdx.x;

  int nwg2 = gridDim.x * gridDim.y;
  int bid = blockIdx.y * gridDim.x + blockIdx.x;
  int swz = (bid & 7) * (nwg2 >> 3) + (bid >> 3);
  int bx = swz % gridDim.x, by = swz / gridDim.x;
  int m0 = by * 128, n0 = bx * BN;
  int z = blockIdx.z;

  const __bf16* Aq = Ap + (long)z * Ksize;
  const __bf16* Bq = Bp + (long)z * Ksize * ldb;

  __shared__ __align__(16) __bf16 Ah[128][40];
  __shared__ __align__(16) __bf16 Bh[BN][40];

  f32x4 acc[4][FN];
  #pragma unroll
  for (int i = 0; i < 4; ++i)
    #pragma unroll
    for (int j = 0; j < FN; ++j)
      #pragma unroll
      for (int k = 0; k < 4; ++k) acc[i][j][k] = 0.f;

  int lane = tid & 63;
  int w = tid >> 6;
  int WR = (w >> 1) * 64, WC = (w & 1) * (BN / 2);
  int fr = lane & 15, kg = lane >> 4;

  const int ar = tid >> 1, acs = (tid & 1) * 16;
  const int bn = tid % BN;
  const int kb = (tid / BN) * KB;

  const __bf16* Abase = Aq + (long)(m0 + ar) * lda + acs;
  const __bf16* Bbase = Bq + (long)kb * ldb + (n0 + bn);

  bf16x8 pa0, pa1;
  __bf16 pbh[KB];
  {
    pa0 = *reinterpret_cast<const bf16x8*>(Abase);
    pa1 = *reinterpret_cast<const bf16x8*>(Abase + 8);
    #pragma unroll
    for (int j = 0; j < KB; ++j) pbh[j] = Bbase[(long)j * ldb];
  }

  for (int k0 = 0; k0 < Ksize; k0 += 32) {
    __syncthreads();
    {
      *reinterpret_cast<bf16x8*>(&Ah[ar][acs]) = pa0;
      *reinterpret_cast<bf16x8*>(&Ah[ar][acs + 8]) = pa1;
      #pragma unroll
      for (int g8 = 0; g8 < KB / 8; ++g8)
        *reinterpret_cast<bf16x8*>(&Bh[bn][kb + g8 * 8]) = *reinterpret_cast<bf16x8*>(&pbh[g8 * 8]);
    }
    __syncthreads();

    if (k0 + 32 < Ksize) {
      const __bf16* As = Abase + (k0 + 32);
      pa0 = *reinterpret_cast<const bf16x8*>(As);
      pa1 = *reinterpret_cast<const bf16x8*>(As + 8);
      const __bf16* Bs = Bbase + (long)(k0 + 32) * ldb;
      #pragma unroll
      for (int j = 0; j < KB; ++j) pbh[j] = Bs[(long)j * ldb];
    }

    bf16x8 ah[4], bh[FN];
    #pragma unroll
    for (int fm = 0; fm < 4; ++fm)
      ah[fm] = *reinterpret_cast<const bf16x8*>(&Ah[WR + fm * 16 + fr][kg * 8]);
    #pragma unroll
    for (int fn = 0; fn < FN; ++fn)
      bh[fn] = *reinterpret_cast<const bf16x8*>(&Bh[WC + fn * 16 + fr][kg * 8]);
    #pragma unroll
    for (int fm = 0; fm < 4; ++fm)
      #pragma unroll
      for (int fn = 0; fn < FN; ++fn)
        acc[fm][fn] = __builtin_amdgcn_mfma_f32_16x16x32_bf16(ah[fm], bh[fn], acc[fm][fn], 0, 0, 0);
  }

  #pragma unroll
  for (int fm = 0; fm < 4; ++fm)
    #pragma unroll
    for (int fn = 0; fn < FN; ++fn)
      #pragma unroll
      for (int i = 0; i < 4; ++i) {
        int rowg = m0 + WR + fm * 16 + kg * 4 + i;
        int coln = n0 + WC + fn * 16 + fr;
        float v = acc[fm][fn][i];
        if (EPI >= 1) v += bias[coln];
        if (EPI == 2) v = 0.5f * v * (1.f + erff(v * 0.70710678118654752f));
        long ci = (long)z * czs + (long)rowg * ldc + coln;
        if (OBF) ((__bf16*)Cp)[ci] = (__bf16)v;
        else     ((float*)Cp)[ci] = v;
      }
}

// ---------- MFMA flash attention, KV-split x2, bf16 qkv input, register prefetch ----------
__global__ __launch_bounds__(256) void flash_attn_split(const __bf16* __restrict__ qkvb,
                                                        const void* __restrict__ mraw,
                                                        const int* __restrict__ flagp,
                                                        float* __restrict__ p0, float* __restrict__ p1,
                                                        float2* __restrict__ ml) {
  __shared__ __align__(16) __bf16 Qs[64][72];
  __shared__ __align__(16) __bf16 Ks[64][72];
  __shared__ __align__(16) __bf16 Vt[64][66];  // V transposed: [d][key]
  __shared__ __align__(16) __bf16 Ps[64][72];
  __shared__ float kmf[64];
  __shared__ float qmf[64];

  int s = blockIdx.z & 1, b = blockIdx.z >> 1;
  int hh = blockIdx.y;
  int q0 = blockIdx.x * 64;
  int tid = threadIdx.x, lane = tid & 63, w = tid >> 6;
  int flag = *flagp;
  int fr = lane & 15, kg = lane >> 4;

  const int sr = tid >> 2;
  const int sc = (tid & 3) * 16;

  {
    const __bf16* Qsrc = qkvb + ((long)(b * Nn + q0 + sr)) * (3 * Dd) + hh * HDd + sc;
    *reinterpret_cast<bf16x8*>(&Qs[sr][sc])     = *reinterpret_cast<const bf16x8*>(Qsrc);
    *reinterpret_cast<bf16x8*>(&Qs[sr][sc + 8]) = *reinterpret_cast<const bf16x8*>(Qsrc + 8);
    if (tid < 64) qmf[tid] = mask_at(mraw, flag, b * Nn + q0 + tid) ? 1.f : 0.f;
  }
  __syncthreads();

  float qm[4];
  #pragma unroll
  for (int i = 0; i < 4; ++i) qm[i] = qmf[16 * w + kg * 4 + i];

  bf16x8 qa[2];
  #pragma unroll
  for (int ks = 0; ks < 2; ++ks)
    qa[ks] = *reinterpret_cast<const bf16x8*>(&Qs[16 * w + fr][ks * 32 + kg * 8]);

  float mrow[4], lrow[4];
  f32x4 accO[4];
  #pragma unroll
  for (int i = 0; i < 4; ++i) { mrow[i] = -INFINITY; lrow[i] = 0.f; }
  #pragma unroll
  for (int t = 0; t < 4; ++t)
    for (int i = 0; i < 4; ++i) accO[t][i] = 0.f;

  const int jbeg = s * (Nn / 2), jend = jbeg + (Nn / 2);

  bf16x8 rk0, rk1, rv0, rv1;
  {
    const __bf16* Ksrc = qkvb + ((long)(b * Nn + jbeg + sr)) * (3 * Dd) + Dd + hh * HDd + sc;
    const __bf16* Vsrc = Ksrc + Dd;
    rk0 = *reinterpret_cast<const bf16x8*>(Ksrc);
    rk1 = *reinterpret_cast<const bf16x8*>(Ksrc + 8);
    rv0 = *reinterpret_cast<const bf16x8*>(Vsrc);
    rv1 = *reinterpret_cast<const bf16x8*>(Vsrc + 8);
  }

  for (int j0 = jbeg; j0 < jend; j0 += 64) {
    __syncthreads();
    {
      *reinterpret_cast<bf16x8*>(&Ks[sr][sc])     = rk0;
      *reinterpret_cast<bf16x8*>(&Ks[sr][sc + 8]) = rk1;
      #pragma unroll
      for (int j = 0; j < 8; ++j) {
        Vt[sc + j][sr]     = rv0[j];
        Vt[sc + 8 + j][sr] = rv1[j];
      }
      if (tid < 64) kmf[tid] = mask_at(mraw, flag, b * Nn + j0 + tid) ? 1.f : 0.f;
    }
    __syncthreads();

    if (j0 + 64 < jend) {
      const __bf16* Ksrc = qkvb + ((long)(b * Nn + j0 + 64 + sr)) * (3 * Dd) + Dd + hh * HDd + sc;
      const __bf16* Vsrc = Ksrc + Dd;
      rk0 = *reinterpret_cast<const bf16x8*>(Ksrc);
      rk1 = *reinterpret_cast<const bf16x8*>(Ksrc + 8);
      rv0 = *reinterpret_cast<const bf16x8*>(Vsrc);
      rv1 = *reinterpret_cast<const bf16x8*>(Vsrc + 8);
    }

    f32x4 sacc[4];
    #pragma unroll
    for (int t = 0; t < 4; ++t)
      for (int i = 0; i < 4; ++i) sacc[t][i] = 0.f;
    #pragma unroll
    for (int ks = 0; ks < 2; ++ks) {
      #pragma unroll
      for (int t = 0; t < 4; ++t) {
        bf16x8 bh = *reinterpret_cast<const bf16x8*>(&Ks[16 * t + fr][ks * 32 + kg * 8]);
        sacc[t] = __builtin_amdgcn_mfma_f32_16x16x32_bf16(qa[ks], bh, sacc[t], 0, 0, 0);
      }
    }

    float sv[4][4];
    float mt[4] = {-INFINITY, -INFINITY, -INFINITY, -INFINITY};
    #pragma unroll
    for (int t = 0; t < 4; ++t) {
      float km = kmf[16 * t + fr];
      #pragma unroll
      for (int i = 0; i < 4; ++i) {
        float sx = (km > 0.f && qm[i] > 0.f) ? sacc[t][i] * 0.125f : NEGF;
        sv[t][i] = sx;
        mt[i] = fmaxf(mt[i], sx);
      }
    }
    #pragma unroll
    for (int off = 8; off; off >>= 1)
      #pragma unroll
      for (int i = 0; i < 4; ++i) mt[i] = fmaxf(mt[i], __shfl_xor(mt[i], off));

    float r[4], psum[4];
    #pragma unroll
    for (int i = 0; i < 4; ++i) {
      float mn = fmaxf(mrow[i], mt[i]);
      r[i] = __expf(mrow[i] - mn);
      mrow[i] = mn;
      psum[i] = 0.f;
    }
    #pragma unroll
    for (int t = 0; t < 4; ++t) {
      #pragma unroll
      for (int i = 0; i < 4; ++i) {
        float p = __expf(sv[t][i] - mrow[i]);
        psum[i] += p;
        Ps[16 * w + kg * 4 + i][16 * t + fr] = (__bf16)p;
      }
    }
    #pragma unroll
    for (int off = 8; off; off >>= 1)
      #pragma unroll
      for (int i = 0; i < 4; ++i) psum[i] += __shfl_xor(psum[i], off);
    #pragma unroll
    for (int i = 0; i < 4; ++i) lrow[i] = lrow[i] * r[i] + psum[i];
    #pragma unroll
    for (int t = 0; t < 4; ++t)
      #pragma unroll
      for (int i = 0; i < 4; ++i) accO[t][i] *= r[i];

    __syncthreads();

    #pragma unroll
    for (int ks = 0; ks < 2; ++ks) {
      bf16x8 pa = *reinterpret_cast<const bf16x8*>(&Ps[16 * w + fr][ks * 32 + kg * 8]);
      #pragma unroll
      for (int t2 = 0; t2 < 4; ++t2) {
        bf16x8 vb = *reinterpret_cast<const bf16x8*>(&Vt[16 * t2 + fr][ks * 32 + kg * 8]);
        accO[t2] = __builtin_amdgcn_mfma_f32_16x16x32_bf16(pa, vb, accO[t2], 0, 0, 0);
      }
    }
  }

  float* op = s ? p1 : p0;
  #pragma unroll
  for (int t2 = 0; t2 < 4; ++t2)
    #pragma unroll
    for (int i = 0; i < 4; ++i) {
      int qrow = q0 + 16 * w + kg * 4 + i;
      int col = 16 * t2 + fr;
      op[((long)(b * Nn + qrow)) * Dd + hh * HDd + col] = accO[t2][i];  // unnormalized
    }
  if (fr == 0) {
    #pragma unroll
    for (int i = 0; i < 4; ++i) {
      int qrow = q0 + 16 * w + kg * 4 + i;
      ml[((long)(s * Bb + b) * Hh + hh) * Nn + qrow] = make_float2(mrow[i], lrow[i]);
    }
  }
}

// ---------- combine two KV-splits -> bf16 attn output ----------
__global__ __launch_bounds__(256) void flash_combine(const float* __restrict__ p0, const float* __restrict__ p1,
                                                     const float2* __restrict__ ml, __bf16* __restrict__ ob) {
  long i4 = (long)blockIdx.x * 256 + threadIdx.x;
  long i = i4 * 4;
  int d = (int)(i % Dd);
  long row = i / Dd;
  int b = (int)(row >> 10), n = (int)(row & (Nn - 1));
  int hh = d >> 6;
  float2 a = ml[((long)b * Hh + hh) * Nn + n];
  float2 c = ml[(((long)Bb + b) * Hh + hh) * Nn + n];
  float M = fmaxf(a.x, c.x);
  float w0 = __expf(a.x - M), w1 = __expf(c.x - M);
  float inv = 1.f / (w0 * a.y + w1 * c.y);
  float4 v0 = reinterpret_cast<const float4*>(p0)[i4];
  float4 v1 = reinterpret_cast<const float4*>(p1)[i4];
  bf16x4 r;
  r[0] = (__bf16)((w0 * v0.x + w1 * v1.x) * inv);
  r[1] = (__bf16)((w0 * v0.y + w1 * v1.y) * inv);
  r[2] = (__bf16)((w0 * v0.z + w1 * v1.z) * inv);
  r[3] = (__bf16)((w0 * v0.w + w1 * v1.w) * inv);
  *reinterpret_cast<bf16x4*>(&ob[i]) = r;
}

// ---------- seq-pool ----------
__global__ __launch_bounds__(256) void pool_score(const float* __restrict__ hn, const float* __restrict__ pw,
                                                  const float* __restrict__ pb, float* __restrict__ s) {
  __shared__ float smem[4];
  int row = blockIdx.x, tid = threadIdx.x;
  const float* x = hn + (size_t)row * Dd;
  float acc = 0.f;
  for (int j = 0; j < 3; ++j) { int c = tid + j * 256; acc += x[c] * pw[c]; }
  acc = block_reduce_sum(acc, smem);
  if (tid == 0) s[row] = acc + pb[0];
}

__global__ __launch_bounds__(256) void pool_softmax(const float* __restrict__ s, float* __restrict__ w) {
  __shared__ float smem[4];
  int b = blockIdx.x, tid = threadIdx.x;
  const float* x = s + b * Nn;
  float v[4];
  for (int j = 0; j < 4; ++j) v[j] = x[tid * 4 + j];
  float mx = fmaxf(fmaxf(v[0], v[1]), fmaxf(v[2], v[3]));
  mx = block_reduce_max(mx, smem);
  float e[4], sum = 0.f;
  for (int j = 0; j < 4; ++j) { e[j] = expf(v[j] - mx); sum += e[j]; }
  sum = block_reduce_sum(sum, smem);
  float inv = 1.f / sum;
  for (int j = 0; j < 4; ++j) w[b * Nn + tid * 4 + j] = e[j] * inv;
}

// stage 1: partial sums over 128-token chunks. grid (Dd/256, 8, Bb), block 256.
__global__ __launch_bounds__(256) void pool_reduce1(const float* __restrict__ hn, const float* __restrict__ w,
                                                    float* __restrict__ part) {
  int d = blockIdx.x * 256 + threadIdx.x;
  int ch = blockIdx.y, b = blockIdx.z;
  int n0 = ch * 128;
  float a0 = 0.f, a1 = 0.f;
  for (int n = n0; n < n0 + 128; n += 2) {
    a0 = fmaf(w[b * Nn + n],     hn[((size_t)(b * Nn + n))     * Dd + d], a0);
    a1 = fmaf(w[b * Nn + n + 1], hn[((size_t)(b * Nn + n + 1)) * Dd + d], a1);
  }
  part[((size_t)(b * 8 + ch)) * Dd + d] = a0 + a1;
}

// stage 2: sum 8 partials. grid (Dd/256, Bb), block 256.
__global__ __launch_bounds__(256) void pool_reduce2(const float* __restrict__ part, float* __restrict__ pooled) {
  int d = blockIdx.x * 256 + threadIdx.x;
  int b = blockIdx.y;
  float s = 0.f;
  #pragma unroll
  for (int ch = 0; ch < 8; ++ch) s += part[((size_t)(b * 8 + ch)) * Dd + d];
  pooled[b * Dd + d] = s;
}

// fc: one class per thread, coalesced over c. grid (4, Bb), block 256.
__global__ __launch_bounds__(256) void fc_kernel(const float* __restrict__ pooled, const float* __restrict__ fw,
                                                 const float* __restrict__ fb, float* __restrict__ out) {
  __shared__ float p[768];
  int b = blockIdx.y, tid = threadIdx.x;
  for (int j = 0; j < 3; ++j) p[tid + j * 256] = pooled[b * Dd + tid + j * 256];
  __syncthreads();
  int c = blockIdx.x * 256 + tid;
  if (c < NCc) {
    float a0 = 0.f, a1 = 0.f, a2 = 0.f, a3 = 0.f;
    #pragma unroll 4
    for (int d = 0; d < Dd; d += 4) {
      a0 = fmaf(p[d],     fw[(size_t)d       * NCc + c], a0);
      a1 = fmaf(p[d + 1], fw[(size_t)(d + 1) * NCc + c], a1);
      a2 = fmaf(p[d + 2], fw[(size_t)(d + 2) * NCc + c], a2);
      a3 = fmaf(p[d + 3], fw[(size_t)(d + 3) * NCc + c], a3);
    }
    out[b * NCc + c] = fb[c] + ((a0 + a1) + (a2 + a3));
  }
}

extern "C" void kernel_launch(void* const* d_in, const int* in_sizes, int n_in,
                              void* d_out, int out_size, void* d_ws, size_t ws_size,
                              hipStream_t stream) {
  const float* x      = (const float*)d_in[0];
  const void*  mask   = d_in[1];
  const float* pe     = (const float*)d_in[2];
  const float* ln0_w  = (const float*)d_in[3];
  const float* ln0_b  = (const float*)d_in[4];
  const float* qkv_w  = (const float*)d_in[5];
  const float* proj_w = (const float*)d_in[6];
  const float* proj_b = (const float*)d_in[7];
  const float* ln1_w  = (const float*)d_in[8];
  const float* ln1_b  = (const float*)d_in[9];
  const float* ff1_w  = (const float*)d_in[10];
  const float* ff1_b  = (const float*)d_in[11];
  const float* ff2_w  = (const float*)d_in[12];
  const float* ff2_b  = (const float*)d_in[13];
  const float* norm_w = (const float*)d_in[14];
  const float* norm_b = (const float*)d_in[15];
  const float* pool_w = (const float*)d_in[16];
  const float* pool_b = (const float*)d_in[17];
  const float* fc_w   = (const float*)d_in[18];
  const float* fc_b   = (const float*)d_in[19];
  float* out = (float*)d_out;

  float* ws = (float*)d_ws;
  float*  h     = ws;                            // Mm*Dd f32 (residual)
  float*  s0    = h + (long)Mm * Dd;             // Mm*Dd f32 scratch
  float*  s1    = s0 + (long)Mm * Dd;            // Mm*Dd f32 scratch
  __bf16* qkvb  = (__bf16*)(s1 + (long)Mm * Dd); // Mm*3*Dd bf16
  __bf16* ob    = qkvb + (long)Mm * 3 * Dd;      // Mm*Dd bf16 (attn out)
  __bf16* yb    = ob + (long)Mm * Dd;            // Mm*Dd bf16 (ln out)

  // Weight-buffer region: big layout (4 separate, 14.2 MB) if ws_size allows; else one shared 4.7 MB.
  const bool bigws = ws_size >= (size_t)54 * 1024 * 1024;
  __bf16* wreg = yb + (long)Mm * Dd;
  __bf16 *wq, *wp, *w1, *w2;
  __bf16* wend;
  if (bigws) {
    wq = wreg;
    wp = wq + (long)Dd * 3 * Dd;
    w1 = wp + (long)Dd * Dd;
    w2 = w1 + (long)Dd * FFf;
    wend = w2 + (long)FFf * Dd;
  } else {
    wq = wp = w1 = w2 = wreg;
    wend = wreg + (long)Dd * FFf;
  }
  float*  tail  = (float*)wend;
  float*  spool  = tail;                         // Mm
  float*  wpool  = spool + Mm;                   // Mm
  float*  pooled = wpool + Mm;                   // Bb*Dd
  float*  ppart  = pooled + Bb * Dd;             // Bb*8*Dd
  float*  mlbuf  = ppart + (long)Bb * 8 * Dd;    // 2*Bb*Hh*Nn float2
  int*    mflag  = (int*)(mlbuf + (long)2 * 2 * Bb * Hh * Nn);
  __bf16* gb = qkvb;     // alias: gelu out Mm*FFf bf16 == qkvb+ob region exactly
  float*  hn = s0;       // final LN out (after loop; s0 free)

  const int n8_qkv  = Dd * 3 * Dd / 8;
  const int n8_proj = Dd * Dd / 8;
  const int n8_ff   = Dd * FFf / 8;
  const int n8_all  = n8_qkv + n8_proj + 2 * n8_ff;

  detect_mask<<<1, 256, 0, stream>>>((const unsigned char*)mask, mflag);
  add_pe_k<<<(Mm * Dd) / 256, 256, 0, stream>>>(x, pe, h);
  ln_kernel<1><<<Mm, 256, 0, stream>>>(h, ln0_w, ln0_b, yb);

  for (int l = 0; l < NLl; ++l) {
    if (bigws) {
      // one conversion launch for all 4 weights of this layer
      cvt_w4<<<(n8_all + 255) / 256, 256, 0, stream>>>(
          qkv_w + (long)l * Dd * 3 * Dd, proj_w + (long)l * Dd * Dd,
          ff1_w + (long)l * Dd * FFf, ff2_w + (long)l * FFf * Dd,
          wq, wp, w1, w2);
    } else {
      cvt_w<<<(n8_qkv + 255) / 256, 256, 0, stream>>>(qkv_w + (long)l * Dd * 3 * Dd, wq, n8_qkv);
    }

    gemm128<64,0,1><<<dim3(3 * Dd / 64, Mm / 128, 1), 256, 0, stream>>>(
        yb, Dd, wq, 3 * Dd, nullptr, qkvb, 3 * Dd, Dd, 0);

    flash_attn_split<<<dim3(Nn / 64, Hh, Bb * 2), 256, 0, stream>>>(
        qkvb, mask, mflag, s0, s1, (float2*)mlbuf);
    flash_combine<<<(Mm * Dd / 4) / 256, 256, 0, stream>>>(s0, s1, (const float2*)mlbuf, ob);

    if (!bigws)
      cvt_w<<<(n8_proj + 255) / 256, 256, 0, stream>>>(proj_w + (long)l * Dd * Dd, wp, n8_proj);
    gemm128<64,0,0><<<dim3(Dd / 64, Mm / 128, 2), 256, 0, stream>>>(
        ob, Dd, wp, Dd, nullptr, s0, Dd, Dd / 2, (long)(s1 - s0));

    res_ln_kernel<1,0><<<Mm, 256, 0, stream>>>(h, s0, s1, proj_b + l * Dd,
                                               ln1_w + l * Dd, ln1_b + l * Dd, yb);

    if (!bigws)
      cvt_w<<<(n8_ff + 255) / 256, 256, 0, stream>>>(ff1_w + (long)l * Dd * FFf, w1, n8_ff);
    gemm128<64,2,1><<<dim3(FFf / 64, Mm / 128, 1), 256, 0, stream>>>(
        yb, Dd, w1, FFf, ff1_b + l * FFf, gb, FFf, Dd, 0);

    if (!bigws)
      cvt_w<<<(n8_ff + 255) / 256, 256, 0, stream>>>(ff2_w + (long)l * FFf * Dd, w2, n8_ff);
    gemm128<64,0,0><<<dim3(Dd / 64, Mm / 128, 2), 256, 0, stream>>>(
        gb, FFf, w2, Dd, nullptr, s0, Dd, FFf / 2, (long)(s1 - s0));

    if (l + 1 < NLl) {
      res_ln_kernel<1,1><<<Mm, 256, 0, stream>>>(h, s0, s1, ff2_b + l * Dd,
                                                 ln0_w + (l + 1) * Dd, ln0_b + (l + 1) * Dd, yb);
    } else {
      res_ln_kernel<0,1><<<Mm, 256, 0, stream>>>(h, s0, s1, ff2_b + l * Dd,
                                                 norm_w, norm_b, hn);
    }
  }

  pool_score<<<Mm, 256, 0, stream>>>(hn, pool_w, pool_b, spool);
  pool_softmax<<<Bb, 256, 0, stream>>>(spool, wpool);
  pool_reduce1<<<dim3(Dd / 256, 8, Bb), 256, 0, stream>>>(hn, wpool, ppart);
  pool_reduce2<<<dim3(Dd / 256, Bb), 256, 0, stream>>>(ppart, pooled);
  fc_kernel<<<dim3(4, Bb), 256, 0, stream>>>(pooled, fc_w, fc_b, out);
}